// Round 9
// baseline (392.431 us; speedup 1.0000x reference)
//
#include <hip/hip_runtime.h>
#include <hip/hip_bf16.h>

// B=8, C=512, N=2048, P=256.
// Round 9: flash-fused scores+softmax+y (online softmax, split-bf16 logits in
// registers -> exact math), replacing 4 scores GEMMs + 4 softmax + y GEMM
// (~190us, ~470MB of f traffic). Other GEMMs back to round-7 shapes (round-8
// 64x64 shrink regressed: intensity loss + L3 didn't absorb re-reads).
// Numerics: theta/phi/scores split-bf16 (3 MFMAs, fp32-class logits);
//           g, P, y, z plain bf16 (post-softmax, not exp-amplified).

typedef __attribute__((ext_vector_type(8))) short short8;
typedef __attribute__((ext_vector_type(4))) float floatx4;

// ---------------- bf16 helpers ----------------
__device__ __forceinline__ unsigned short f2bf(float v) {
    __hip_bfloat16 h = __float2bfloat16(v);
    return *(unsigned short*)&h;
}
__device__ __forceinline__ float bf2f(unsigned short u) {
    __hip_bfloat16 h;
    *(unsigned short*)&h = u;
    return __bfloat162float(h);
}

// transpose + hi/lo split: X [R][N] fp32 -> Thi/Tlo [N][R] bf16 (batched over z)
__global__ __launch_bounds__(256) void transpose_split(
    const float* __restrict__ X, unsigned short* __restrict__ Thi,
    unsigned short* __restrict__ Tlo, int R, int N)
{
    X   += (long)blockIdx.z * R * N;
    Thi += (long)blockIdx.z * N * R;
    Tlo += (long)blockIdx.z * N * R;
    __shared__ float s[32][33];
    const int tx = threadIdx.x & 31, ty = threadIdx.x >> 5;
    const int n0 = blockIdx.x * 32, r0 = blockIdx.y * 32;
#pragma unroll
    for (int r = 0; r < 4; ++r)
        s[ty + r * 8][tx] = X[(long)(r0 + ty + r * 8) * N + n0 + tx];
    __syncthreads();
#pragma unroll
    for (int r = 0; r < 4; ++r) {
        const int n = ty + r * 8;
        const float v = s[tx][n];
        const unsigned short hi = f2bf(v);
        const unsigned short lo = f2bf(v - bf2f(hi));
        Thi[(long)(n0 + n) * R + r0 + tx] = hi;
        Tlo[(long)(n0 + n) * R + r0 + tx] = lo;
    }
}

// concat [Wth; Wph] rows and hi/lo split: out [2P][C]
__global__ __launch_bounds__(256) void split_w2(
    const float* __restrict__ Wth, const float* __restrict__ Wph,
    unsigned short* __restrict__ Whi, unsigned short* __restrict__ Wlo, int PC)
{
    const int i = blockIdx.x * 256 + threadIdx.x;
    if (i < 2 * PC) {
        const float v = (i < PC) ? Wth[i] : Wph[i - PC];
        const unsigned short hi = f2bf(v);
        Whi[i] = hi;
        Wlo[i] = f2bf(v - bf2f(hi));
    }
}

__global__ __launch_bounds__(256) void cast_bf16(
    const float* __restrict__ X, unsigned short* __restrict__ Y)
{
    const long i = ((long)blockIdx.x * 256 + threadIdx.x) * 4;
    const float4 v = *(const float4*)&X[i];
    ushort4 o;
    o.x = f2bf(v.x); o.y = f2bf(v.y); o.z = f2bf(v.z); o.w = f2bf(v.w);
    *(ushort4*)&Y[i] = o;
}

// ---------------- MFMA GEMM (register-prefetch pipeline, round 7) ----------------
// C[M][N] = A[M][K] * B[N][K]^T, bf16 K-contiguous inputs, fp32 accum.
// OUTMODE: 0 fp32, 1 bf16, 2 hi/lo split bf16, 3 bf16 + BN partials scratch
//          (slot = (bz*gridDim.x+bx)*2 + (wn>>6); [C][256] scratch).
#define BK 32

template <bool SPLIT, int OUTMODE, int FM, int FN>
__global__ __launch_bounds__(256) void mfma_gemm(
    const unsigned short* __restrict__ Ahi, const unsigned short* __restrict__ Alo,
    const unsigned short* __restrict__ Bhi, const unsigned short* __restrict__ Blo,
    void* __restrict__ Cout, void* __restrict__ Cout2,
    int K, int lda, int ldb, int ldc,
    long sA, long sB, long sC,
    float* __restrict__ S1, float* __restrict__ S2)
{
    constexpr int MTM = FM * 32, MTN = FN * 32;
    constexpr int SA = FM / 2, SB = FN / 2;

    Ahi += (long)blockIdx.z * sA;
    Bhi += (long)blockIdx.z * sB;
    if (SPLIT) { Alo += (long)blockIdx.z * sA; Blo += (long)blockIdx.z * sB; }
    float* Cf = (float*)Cout + (long)blockIdx.z * sC;
    unsigned short* Ch = (unsigned short*)Cout + (long)blockIdx.z * sC;
    unsigned short* Cl = (unsigned short*)Cout2 + (long)blockIdx.z * sC;

    __shared__ unsigned short AsH[MTM * BK], BsH[MTN * BK];
    __shared__ unsigned short AsL[SPLIT ? MTM * BK : 8], BsL[SPLIT ? MTN * BK : 8];

    const int tid = threadIdx.x;
    const int wid = tid >> 6, lane = tid & 63;
    const int wm = (wid >> 1) * (FM * 16), wn = (wid & 1) * (FN * 16);
    const int l15 = lane & 15, quad = lane >> 4;
    const int m0 = blockIdx.y * MTM, n0 = blockIdx.x * MTN;

    int arow[SA], acol[SA], brow[SB], bcol[SB];
#pragma unroll
    for (int t = 0; t < SA; ++t) {
        const int gid = t * 256 + tid;
        arow[t] = gid >> 2; acol[t] = (gid & 3) * 8;
    }
#pragma unroll
    for (int t = 0; t < SB; ++t) {
        const int gid = t * 256 + tid;
        brow[t] = gid >> 2; bcol[t] = (gid & 3) * 8;
    }

    short8 pa[SA], pb[SB], paL[SPLIT ? SA : 1], pbL[SPLIT ? SB : 1];

    auto loadTiles = [&](int k0) {
#pragma unroll
        for (int t = 0; t < SA; ++t) {
            const long o = (long)(m0 + arow[t]) * lda + k0 + acol[t];
            pa[t] = *(const short8*)&Ahi[o];
            if (SPLIT) paL[t] = *(const short8*)&Alo[o];
        }
#pragma unroll
        for (int t = 0; t < SB; ++t) {
            const long o = (long)(n0 + brow[t]) * ldb + k0 + bcol[t];
            pb[t] = *(const short8*)&Bhi[o];
            if (SPLIT) pbL[t] = *(const short8*)&Blo[o];
        }
    };
    auto writeTiles = [&]() {
#pragma unroll
        for (int t = 0; t < SA; ++t) {
            *(short8*)&AsH[arow[t] * BK + acol[t]] = pa[t];
            if (SPLIT) *(short8*)&AsL[arow[t] * BK + acol[t]] = paL[t];
        }
#pragma unroll
        for (int t = 0; t < SB; ++t) {
            *(short8*)&BsH[brow[t] * BK + bcol[t]] = pb[t];
            if (SPLIT) *(short8*)&BsL[brow[t] * BK + bcol[t]] = pbL[t];
        }
    };

    floatx4 acc[FM][FN];
#pragma unroll
    for (int i = 0; i < FM; ++i)
#pragma unroll
        for (int j = 0; j < FN; ++j) acc[i][j] = (floatx4){0.f, 0.f, 0.f, 0.f};

    const int iters = K / BK;
    loadTiles(0);
    writeTiles();
    __syncthreads();

    for (int it = 0; it < iters; ++it) {
        if (it + 1 < iters) loadTiles((it + 1) * BK);

        short8 ah[FM], bh[FN], al[SPLIT ? FM : 1], bl[SPLIT ? FN : 1];
#pragma unroll
        for (int i = 0; i < FM; ++i) {
            ah[i] = *(const short8*)&AsH[(wm + i * 16 + l15) * BK + quad * 8];
            if (SPLIT) al[i] = *(const short8*)&AsL[(wm + i * 16 + l15) * BK + quad * 8];
        }
#pragma unroll
        for (int j = 0; j < FN; ++j) {
            bh[j] = *(const short8*)&BsH[(wn + j * 16 + l15) * BK + quad * 8];
            if (SPLIT) bl[j] = *(const short8*)&BsL[(wn + j * 16 + l15) * BK + quad * 8];
        }
#pragma unroll
        for (int i = 0; i < FM; ++i)
#pragma unroll
            for (int j = 0; j < FN; ++j) {
                acc[i][j] = __builtin_amdgcn_mfma_f32_16x16x32_bf16(ah[i], bh[j], acc[i][j], 0, 0, 0);
                if (SPLIT) {
                    acc[i][j] = __builtin_amdgcn_mfma_f32_16x16x32_bf16(ah[i], bl[j], acc[i][j], 0, 0, 0);
                    acc[i][j] = __builtin_amdgcn_mfma_f32_16x16x32_bf16(al[i], bh[j], acc[i][j], 0, 0, 0);
                }
            }

        if (it + 1 < iters) {
            __syncthreads();
            writeTiles();
            __syncthreads();
        }
    }

#pragma unroll
    for (int i = 0; i < FM; ++i)
#pragma unroll
        for (int j = 0; j < FN; ++j) {
            const int m = m0 + wm + i * 16 + quad * 4;
            const int n = n0 + wn + j * 16 + l15;
#pragma unroll
            for (int r = 0; r < 4; ++r) {
                const float v = acc[i][j][r];
                const long idx = (long)(m + r) * ldc + n;
                if (OUTMODE == 0) {
                    Cf[idx] = v;
                } else if (OUTMODE == 1 || OUTMODE == 3) {
                    Ch[idx] = f2bf(v);
                } else {
                    const unsigned short hi = f2bf(v);
                    Ch[idx] = hi;
                    Cl[idx] = f2bf(v - bf2f(hi));
                }
            }
        }

    if (OUTMODE == 3) {
        const int slot = (blockIdx.z * gridDim.x + blockIdx.x) * 2 + (wn >> 6);
#pragma unroll
        for (int i = 0; i < FM; ++i)
#pragma unroll
            for (int r = 0; r < 4; ++r) {
                float s = 0.f, q = 0.f;
#pragma unroll
                for (int j = 0; j < FN; ++j) {
                    const float v = acc[i][j][r];
                    s += v; q += v * v;
                }
#pragma unroll
                for (int msk = 1; msk < 16; msk <<= 1) {
                    s += __shfl_xor(s, msk, 64);
                    q += __shfl_xor(q, msk, 64);
                }
                if (l15 == 0) {
                    const int row = m0 + wm + i * 16 + quad * 4 + r;
                    S1[(long)row * 256 + slot] = s;
                    S2[(long)row * 256 + slot] = q;
                }
            }
    }
}

// ---------------- fused scores+softmax+y (flash-style) ----------------
// Per block: one batch b, 64 q-rows. Online softmax over 16 key-tiles of 128.
// S phase: waves split the 128-key tile (32 keys each), split-bf16 logits
//   (3 MFMAs) in fp32 regs — exact.
// P = exp(S - m_running) -> bf16 via LDS (C-layout -> A-layout transform).
// PV phase: waves split p (64 each); O[64q][64p] fp32 regs, rescaled by alpha
//   each tile; final O/l -> yT bf16 [B][N][P].
#define QT 64
#define MT2 128
#define PSTR 72     // LDS row stride (64 + 8 pad) for theta/phi/G tiles
#define PPAD 136    // LDS row stride (128 + 8 pad) for P

__global__ __launch_bounds__(256) void fused_attn(
    const unsigned short* __restrict__ thphH,
    const unsigned short* __restrict__ thphL,
    const unsigned short* __restrict__ gbf,
    unsigned short* __restrict__ ybf,
    int N, int P)
{
    const int id = blockIdx.x;
    const int b  = id & 7;            // XCD-swizzle: one batch per XCD (heuristic)
    const int qt = id >> 3;
    const int P2 = 2 * P;

    const unsigned short* thB = thphH + (long)b * N * P2;
    const unsigned short* tlB = thphL + (long)b * N * P2;
    const unsigned short* gB  = gbf   + (long)b * P * N;
    unsigned short*       yB  = ybf   + (long)b * N * P;

    __shared__ unsigned short Th[QT * PSTR],  Tl[QT * PSTR];    // theta k-chunk
    __shared__ unsigned short Fh[MT2 * PSTR], Fl[MT2 * PSTR];   // phi k-chunk
    __shared__ unsigned short Pw[QT * PPAD];                    // P (bf16)
    __shared__ unsigned short Gs[256 * PSTR];                   // G m-chunk (all p)
    __shared__ float wmaxS[4][QT], lpartS[4][QT];
    __shared__ float mrunS[QT], lrunS[QT], alphaS[QT];

    const int tid = threadIdx.x;
    const int wid = tid >> 6, lane = tid & 63;
    const int l15 = lane & 15, quad = lane >> 4;
    const int q0 = qt * QT;

    if (tid < QT) { mrunS[tid] = -1e30f; lrunS[tid] = 0.f; }

    floatx4 oacc[4][4];
#pragma unroll
    for (int i = 0; i < 4; ++i)
#pragma unroll
        for (int j = 0; j < 4; ++j) oacc[i][j] = (floatx4){0.f, 0.f, 0.f, 0.f};

    __syncthreads();

    for (int mt = 0; mt < N / MT2; ++mt) {
        const int m0 = mt * MT2;

        // ---- S phase: wave's m-slice = [wid*32, wid*32+32) ----
        floatx4 sacc[4][2];
#pragma unroll
        for (int i = 0; i < 4; ++i)
#pragma unroll
            for (int j = 0; j < 2; ++j) sacc[i][j] = (floatx4){0.f, 0.f, 0.f, 0.f};

        for (int kc = 0; kc < P / 64; ++kc) {       // 4 chunks of 64 k
            __syncthreads();                        // prev readers of Th/Fh done
            // stage theta [64][64] (2 seg/thread) + phi [128][64] (4 seg/thread)
#pragma unroll
            for (int s = 0; s < 2; ++s) {
                const int gid = s * 256 + tid;
                const int row = gid >> 3, c8 = (gid & 7) * 8;
                const long go = (long)(q0 + row) * P2 + kc * 64 + c8;
                *(short8*)&Th[row * PSTR + c8] = *(const short8*)&thB[go];
                *(short8*)&Tl[row * PSTR + c8] = *(const short8*)&tlB[go];
            }
#pragma unroll
            for (int s = 0; s < 4; ++s) {
                const int gid = s * 256 + tid;
                const int row = gid >> 3, c8 = (gid & 7) * 8;
                const long go = (long)(m0 + row) * P2 + P + kc * 64 + c8;
                *(short8*)&Fh[row * PSTR + c8] = *(const short8*)&thB[go];
                *(short8*)&Fl[row * PSTR + c8] = *(const short8*)&tlB[go];
            }
            __syncthreads();
#pragma unroll
            for (int ks = 0; ks < 2; ++ks) {
                short8 ah[4], al[4], bh[2], bl[2];
#pragma unroll
                for (int i = 0; i < 4; ++i) {
                    const int ro = (i * 16 + l15) * PSTR + ks * 32 + quad * 8;
                    ah[i] = *(const short8*)&Th[ro];
                    al[i] = *(const short8*)&Tl[ro];
                }
#pragma unroll
                for (int j = 0; j < 2; ++j) {
                    const int ro = (wid * 32 + j * 16 + l15) * PSTR + ks * 32 + quad * 8;
                    bh[j] = *(const short8*)&Fh[ro];
                    bl[j] = *(const short8*)&Fl[ro];
                }
                // 3 passes -> dependency distance 8
#pragma unroll
                for (int i = 0; i < 4; ++i)
#pragma unroll
                    for (int j = 0; j < 2; ++j)
                        sacc[i][j] = __builtin_amdgcn_mfma_f32_16x16x32_bf16(ah[i], bh[j], sacc[i][j], 0, 0, 0);
#pragma unroll
                for (int i = 0; i < 4; ++i)
#pragma unroll
                    for (int j = 0; j < 2; ++j)
                        sacc[i][j] = __builtin_amdgcn_mfma_f32_16x16x32_bf16(ah[i], bl[j], sacc[i][j], 0, 0, 0);
#pragma unroll
                for (int i = 0; i < 4; ++i)
#pragma unroll
                    for (int j = 0; j < 2; ++j)
                        sacc[i][j] = __builtin_amdgcn_mfma_f32_16x16x32_bf16(al[i], bh[j], sacc[i][j], 0, 0, 0);
            }
        }

        // ---- online softmax ----
        // per-wave row max over its 32 keys (C-layout: row = i*16+quad*4+r, col=l15)
#pragma unroll
        for (int i = 0; i < 4; ++i)
#pragma unroll
            for (int r = 0; r < 4; ++r) {
                float v = fmaxf(sacc[i][0][r], sacc[i][1][r]);
                v = fmaxf(v, __shfl_xor(v, 1, 64));
                v = fmaxf(v, __shfl_xor(v, 2, 64));
                v = fmaxf(v, __shfl_xor(v, 4, 64));
                v = fmaxf(v, __shfl_xor(v, 8, 64));
                if (l15 == 0) wmaxS[wid][i * 16 + quad * 4 + r] = v;
            }
        __syncthreads();
        if (tid < QT) {
            const float tm = fmaxf(fmaxf(wmaxS[0][tid], wmaxS[1][tid]),
                                   fmaxf(wmaxS[2][tid], wmaxS[3][tid]));
            const float mo = mrunS[tid];
            const float mn = fmaxf(mo, tm);
            mrunS[tid] = mn;
            alphaS[tid] = __expf(mo - mn);
        }
        __syncthreads();
        // P = exp(S - m), bf16 into Pw; per-wave row sums
#pragma unroll
        for (int i = 0; i < 4; ++i)
#pragma unroll
            for (int r = 0; r < 4; ++r) {
                const int row = i * 16 + quad * 4 + r;
                const float mn = mrunS[row];
                const float p0 = __expf(sacc[i][0][r] - mn);
                const float p1 = __expf(sacc[i][1][r] - mn);
                Pw[row * PPAD + wid * 32 + l15]      = f2bf(p0);
                Pw[row * PPAD + wid * 32 + 16 + l15] = f2bf(p1);
                float s = p0 + p1;
                s += __shfl_xor(s, 1, 64);
                s += __shfl_xor(s, 2, 64);
                s += __shfl_xor(s, 4, 64);
                s += __shfl_xor(s, 8, 64);
                if (l15 == 0) lpartS[wid][row] = s;
            }
        // rescale O by alpha (each wave's own O slice)
#pragma unroll
        for (int i = 0; i < 4; ++i) {
            float a[4];
#pragma unroll
            for (int r = 0; r < 4; ++r) a[r] = alphaS[i * 16 + quad * 4 + r];
#pragma unroll
            for (int pj = 0; pj < 4; ++pj)
#pragma unroll
                for (int r = 0; r < 4; ++r) oacc[i][pj][r] *= a[r];
        }
        __syncthreads();          // Pw + lpart complete
        if (tid < QT) {
            lrunS[tid] = lrunS[tid] * alphaS[tid]
                       + lpartS[0][tid] + lpartS[1][tid] + lpartS[2][tid] + lpartS[3][tid];
        }

        // ---- PV phase: wave p-slice = [wid*64, wid*64+64) ----
        for (int mc = 0; mc < 2; ++mc) {            // 2 chunks of 64 keys
            __syncthreads();                        // prev readers of Gs done
#pragma unroll
            for (int s = 0; s < 8; ++s) {
                const int gid = s * 256 + tid;
                const int row = gid >> 3, c8 = (gid & 7) * 8;
                *(short8*)&Gs[row * PSTR + c8] =
                    *(const short8*)&gB[(long)row * N + m0 + mc * 64 + c8];
            }
            __syncthreads();
#pragma unroll
            for (int ks = 0; ks < 2; ++ks) {
                short8 af[4], bg[4];
#pragma unroll
                for (int i = 0; i < 4; ++i)
                    af[i] = *(const short8*)&Pw[(i * 16 + l15) * PPAD + mc * 64 + ks * 32 + quad * 8];
#pragma unroll
                for (int pj = 0; pj < 4; ++pj)
                    bg[pj] = *(const short8*)&Gs[(wid * 64 + pj * 16 + l15) * PSTR + ks * 32 + quad * 8];
#pragma unroll
                for (int i = 0; i < 4; ++i)
#pragma unroll
                    for (int pj = 0; pj < 4; ++pj)
                        oacc[i][pj] = __builtin_amdgcn_mfma_f32_16x16x32_bf16(af[i], bg[pj], oacc[i][pj], 0, 0, 0);
            }
        }
    }

    // ---- finalize: O / l -> yT bf16 ----
    __syncthreads();
    if (tid < QT) alphaS[tid] = 1.0f / lrunS[tid];   // reuse as linv
    __syncthreads();
#pragma unroll
    for (int i = 0; i < 4; ++i) {
        float li[4];
#pragma unroll
        for (int r = 0; r < 4; ++r) li[r] = alphaS[i * 16 + quad * 4 + r];
#pragma unroll
        for (int pj = 0; pj < 4; ++pj)
#pragma unroll
            for (int r = 0; r < 4; ++r) {
                const int row = q0 + i * 16 + quad * 4 + r;
                const int col = wid * 64 + pj * 16 + l15;
                yB[(long)row * P + col] = f2bf(oacc[i][pj][r] * li[r]);
            }
    }
}

// ---------------- BN finalize + apply ----------------
__global__ __launch_bounds__(256) void bn_finalize(
    const float* __restrict__ p1, const float* __restrict__ p2,
    float* __restrict__ mean, float* __restrict__ rstd, float cnt)
{
    const int c = blockIdx.x, t = threadIdx.x;
    __shared__ float rs[256], rq[256];
    rs[t] = p1[(long)c * 256 + t];
    rq[t] = p2[(long)c * 256 + t];
    __syncthreads();
    for (int st = 128; st > 0; st >>= 1) {
        if (t < st) { rs[t] += rs[t + st]; rq[t] += rq[t + st]; }
        __syncthreads();
    }
    if (t == 0) {
        const float m = rs[0] / cnt;
        mean[c] = m;
        rstd[c] = rsqrtf(rq[0] / cnt - m * m + 1e-5f);
    }
}

__global__ __launch_bounds__(256) void bn_apply_bf(
    const unsigned short* __restrict__ z, const float* __restrict__ x,
    const float* __restrict__ mean, const float* __restrict__ rstd,
    const float* __restrict__ gamma, const float* __restrict__ beta,
    float* __restrict__ out, int C, int N)
{
    const long i = ((long)blockIdx.x * 256 + threadIdx.x) * 8;
    const int c = (int)((i / N) % C);
    const float mu = mean[c], rs = rstd[c], ga = gamma[c], be = beta[c];
    const ushort4 z0 = *(const ushort4*)&z[i];
    const ushort4 z1 = *(const ushort4*)&z[i + 4];
    const float4 x0 = *(const float4*)&x[i];
    const float4 x1 = *(const float4*)&x[i + 4];
    float4 o0, o1;
    o0.x = (bf2f(z0.x) - mu) * rs * ga + be + x0.x;
    o0.y = (bf2f(z0.y) - mu) * rs * ga + be + x0.y;
    o0.z = (bf2f(z0.z) - mu) * rs * ga + be + x0.z;
    o0.w = (bf2f(z0.w) - mu) * rs * ga + be + x0.w;
    o1.x = (bf2f(z1.x) - mu) * rs * ga + be + x1.x;
    o1.y = (bf2f(z1.y) - mu) * rs * ga + be + x1.y;
    o1.z = (bf2f(z1.z) - mu) * rs * ga + be + x1.z;
    o1.w = (bf2f(z1.w) - mu) * rs * ga + be + x1.w;
    *(float4*)&out[i] = o0;
    *(float4*)&out[i + 4] = o1;
}

extern "C" void kernel_launch(void* const* d_in, const int* in_sizes, int n_in,
                              void* d_out, int out_size, void* d_ws, size_t ws_size,
                              hipStream_t stream)
{
    const int B = 8, C = 512, N = 2048, P = 256;
    const float* x      = (const float*)d_in[0];
    const float* Wg     = (const float*)d_in[1];
    const float* Wtheta = (const float*)d_in[2];
    const float* Wphi   = (const float*)d_in[3];
    const float* Wz     = (const float*)d_in[4];
    const float* gamma  = (const float*)d_in[5];
    const float* beta   = (const float*)d_in[6];
    float* out = (float*)d_out;

    // ---- workspace layout (float units), same as round 7 ----
    float* ws = (float*)d_ws;
    const long NCle = (long)N * C;            // 1,048,576 per batch (= N*2P)
    const long NP   = (long)N * P;            // 524,288 per batch
    const long R0   = (long)B * NCle;         // 8.39M floats
    unsigned short* xtH   = (unsigned short*)ws;                // B*N*C
    unsigned short* xtL   = xtH + B * NCle;
    unsigned short* zbf   = (unsigned short*)ws;                // aliases xt (dead)
    unsigned short* thphH = (unsigned short*)(ws + R0);         // B*N*2P
    unsigned short* thphL = thphH + B * NCle;                   // B*N*2P
    unsigned short* gbf   = (unsigned short*)(ws + 2 * R0);     // B*P*N
    unsigned short* fbf   = gbf + B * NP;                       // (unused now)
    unsigned short* ybf   = fbf + (long)B * N * N;              // B*N*P
    unsigned short* W2H   = ybf + B * NP;                       // 2P*C
    unsigned short* W2L   = W2H + 2L * P * C;
    unsigned short* WgB   = W2L + 2L * P * C;                   // P*C
    unsigned short* WzB   = WgB + (long)P * C;
    // BN scratch aliases thph region (dead after fused_attn): [C][256] x2
    float*          bnp1  = ws + R0;
    float*          bnp2  = bnp1 + (long)C * 256;
    float*          mean  = bnp2 + (long)C * 256;
    float*          rstd  = mean + C;

    const long sX = (long)C * N;
    const int  P2 = 2 * P;

    // 1: transpose+split x -> xT hi/lo [B][N][C]
    transpose_split<<<dim3(N / 32, C / 32, B), 256, 0, stream>>>(x, xtH, xtL, C, N);
    // 2: weight preps
    split_w2<<<(2 * P * C + 255) / 256, 256, 0, stream>>>(Wtheta, Wphi, W2H, W2L, P * C);
    cast_bf16<<<P * C / 1024, 256, 0, stream>>>(Wg, WgB);
    cast_bf16<<<P * C / 1024, 256, 0, stream>>>(Wz, WzB);

    // 3: thph [B][N][2P] = xT @ W2^T (split in/out); R7 shape: 128x128, 512 blocks
    mfma_gemm<true, 2, 4, 4><<<dim3(P2 / 128, N / 128, B), 256, 0, stream>>>(
        xtH, xtL, W2H, W2L, thphH, thphL, C, C, C, P2, NCle, 0, NCle, nullptr, nullptr);
    // 4: g [B][P][N] = Wg @ xT^T (plain, bf16 out); R7 shape: 64x128, 512 blocks
    mfma_gemm<false, 1, 2, 4><<<dim3(N / 128, P / 64, B), 256, 0, stream>>>(
        WgB, WgB, xtH, xtH, gbf, gbf, C, C, C, N, 0, NCle, NP, nullptr, nullptr);

    // 5: fused scores+softmax+y -> yT [B][N][P] bf16 (256 blocks, 1/CU)
    fused_attn<<<dim3(N / QT * B), 256, 0, stream>>>(thphH, thphL, gbf, ybf, N, P);

    // 6: z [B][C][N] bf16 = Wz @ yT^T, BN partials (thph dead now); R7 shape
    mfma_gemm<false, 3, 4, 4><<<dim3(N / 128, C / 128, B), 256, 0, stream>>>(
        WzB, WzB, ybf, ybf, zbf, zbf, P, P, P, N, 0, NP, sX, bnp1, bnp2);

    // 7: BN finalize + apply + residual
    bn_finalize<<<C, 256, 0, stream>>>(bnp1, bnp2, mean, rstd, (float)B * N);
    bn_apply_bf<<<(int)((B * sX) / 2048), 256, 0, stream>>>(zbf, x, mean, rstd, gamma, beta, out, C, N);
}

// Round 10
// 297.377 us; speedup vs baseline: 1.3196x; 1.3196x over previous
//
#include <hip/hip_runtime.h>
#include <hip/hip_bf16.h>

// B=8, C=512, N=2048, P=256.
// Round 10: fused attention v2 — wave-private q-tiles (16 rows/wave):
//   softmax state (m,l,alpha) fully in registers (no cross-wave barriers),
//   theta A-fragments hoisted into registers (loaded once, not 64x),
//   register-prefetch staging for phi/G chunks (R7 pattern),
//   padded LDS strides (2-way-only bank aliasing).
// Traffic already proven good in R9 (FETCH 20MB, HBM 1.6%); this fixes the
// latency structure (231us -> target 60-90us).
// Numerics: theta/phi/scores split-bf16 (3 MFMAs, fp32-class logits);
//           g, P, y, z plain bf16 (post-softmax, not exp-amplified).

typedef __attribute__((ext_vector_type(8))) short short8;
typedef __attribute__((ext_vector_type(4))) float floatx4;

// ---------------- bf16 helpers ----------------
__device__ __forceinline__ unsigned short f2bf(float v) {
    __hip_bfloat16 h = __float2bfloat16(v);
    return *(unsigned short*)&h;
}
__device__ __forceinline__ float bf2f(unsigned short u) {
    __hip_bfloat16 h;
    *(unsigned short*)&h = u;
    return __bfloat162float(h);
}

// transpose + hi/lo split: X [R][N] fp32 -> Thi/Tlo [N][R] bf16 (batched over z)
__global__ __launch_bounds__(256) void transpose_split(
    const float* __restrict__ X, unsigned short* __restrict__ Thi,
    unsigned short* __restrict__ Tlo, int R, int N)
{
    X   += (long)blockIdx.z * R * N;
    Thi += (long)blockIdx.z * N * R;
    Tlo += (long)blockIdx.z * N * R;
    __shared__ float s[32][33];
    const int tx = threadIdx.x & 31, ty = threadIdx.x >> 5;
    const int n0 = blockIdx.x * 32, r0 = blockIdx.y * 32;
#pragma unroll
    for (int r = 0; r < 4; ++r)
        s[ty + r * 8][tx] = X[(long)(r0 + ty + r * 8) * N + n0 + tx];
    __syncthreads();
#pragma unroll
    for (int r = 0; r < 4; ++r) {
        const int n = ty + r * 8;
        const float v = s[tx][n];
        const unsigned short hi = f2bf(v);
        const unsigned short lo = f2bf(v - bf2f(hi));
        Thi[(long)(n0 + n) * R + r0 + tx] = hi;
        Tlo[(long)(n0 + n) * R + r0 + tx] = lo;
    }
}

// concat [Wth; Wph] rows and hi/lo split: out [2P][C]
__global__ __launch_bounds__(256) void split_w2(
    const float* __restrict__ Wth, const float* __restrict__ Wph,
    unsigned short* __restrict__ Whi, unsigned short* __restrict__ Wlo, int PC)
{
    const int i = blockIdx.x * 256 + threadIdx.x;
    if (i < 2 * PC) {
        const float v = (i < PC) ? Wth[i] : Wph[i - PC];
        const unsigned short hi = f2bf(v);
        Whi[i] = hi;
        Wlo[i] = f2bf(v - bf2f(hi));
    }
}

__global__ __launch_bounds__(256) void cast_bf16(
    const float* __restrict__ X, unsigned short* __restrict__ Y)
{
    const long i = ((long)blockIdx.x * 256 + threadIdx.x) * 4;
    const float4 v = *(const float4*)&X[i];
    ushort4 o;
    o.x = f2bf(v.x); o.y = f2bf(v.y); o.z = f2bf(v.z); o.w = f2bf(v.w);
    *(ushort4*)&Y[i] = o;
}

// ---------------- MFMA GEMM (register-prefetch pipeline, round 7) ----------------
// C[M][N] = A[M][K] * B[N][K]^T, bf16 K-contiguous inputs, fp32 accum.
// OUTMODE: 0 fp32, 1 bf16, 2 hi/lo split bf16, 3 bf16 + BN partials scratch
//          (slot = (bz*gridDim.x+bx)*2 + (wn>>6); [C][256] scratch).
#define BK 32

template <bool SPLIT, int OUTMODE, int FM, int FN>
__global__ __launch_bounds__(256) void mfma_gemm(
    const unsigned short* __restrict__ Ahi, const unsigned short* __restrict__ Alo,
    const unsigned short* __restrict__ Bhi, const unsigned short* __restrict__ Blo,
    void* __restrict__ Cout, void* __restrict__ Cout2,
    int K, int lda, int ldb, int ldc,
    long sA, long sB, long sC,
    float* __restrict__ S1, float* __restrict__ S2)
{
    constexpr int MTM = FM * 32, MTN = FN * 32;
    constexpr int SA = FM / 2, SB = FN / 2;

    Ahi += (long)blockIdx.z * sA;
    Bhi += (long)blockIdx.z * sB;
    if (SPLIT) { Alo += (long)blockIdx.z * sA; Blo += (long)blockIdx.z * sB; }
    float* Cf = (float*)Cout + (long)blockIdx.z * sC;
    unsigned short* Ch = (unsigned short*)Cout + (long)blockIdx.z * sC;
    unsigned short* Cl = (unsigned short*)Cout2 + (long)blockIdx.z * sC;

    __shared__ unsigned short AsH[MTM * BK], BsH[MTN * BK];
    __shared__ unsigned short AsL[SPLIT ? MTM * BK : 8], BsL[SPLIT ? MTN * BK : 8];

    const int tid = threadIdx.x;
    const int wid = tid >> 6, lane = tid & 63;
    const int wm = (wid >> 1) * (FM * 16), wn = (wid & 1) * (FN * 16);
    const int l15 = lane & 15, quad = lane >> 4;
    const int m0 = blockIdx.y * MTM, n0 = blockIdx.x * MTN;

    int arow[SA], acol[SA], brow[SB], bcol[SB];
#pragma unroll
    for (int t = 0; t < SA; ++t) {
        const int gid = t * 256 + tid;
        arow[t] = gid >> 2; acol[t] = (gid & 3) * 8;
    }
#pragma unroll
    for (int t = 0; t < SB; ++t) {
        const int gid = t * 256 + tid;
        brow[t] = gid >> 2; bcol[t] = (gid & 3) * 8;
    }

    short8 pa[SA], pb[SB], paL[SPLIT ? SA : 1], pbL[SPLIT ? SB : 1];

    auto loadTiles = [&](int k0) {
#pragma unroll
        for (int t = 0; t < SA; ++t) {
            const long o = (long)(m0 + arow[t]) * lda + k0 + acol[t];
            pa[t] = *(const short8*)&Ahi[o];
            if (SPLIT) paL[t] = *(const short8*)&Alo[o];
        }
#pragma unroll
        for (int t = 0; t < SB; ++t) {
            const long o = (long)(n0 + brow[t]) * ldb + k0 + bcol[t];
            pb[t] = *(const short8*)&Bhi[o];
            if (SPLIT) pbL[t] = *(const short8*)&Blo[o];
        }
    };
    auto writeTiles = [&]() {
#pragma unroll
        for (int t = 0; t < SA; ++t) {
            *(short8*)&AsH[arow[t] * BK + acol[t]] = pa[t];
            if (SPLIT) *(short8*)&AsL[arow[t] * BK + acol[t]] = paL[t];
        }
#pragma unroll
        for (int t = 0; t < SB; ++t) {
            *(short8*)&BsH[brow[t] * BK + bcol[t]] = pb[t];
            if (SPLIT) *(short8*)&BsL[brow[t] * BK + bcol[t]] = pbL[t];
        }
    };

    floatx4 acc[FM][FN];
#pragma unroll
    for (int i = 0; i < FM; ++i)
#pragma unroll
        for (int j = 0; j < FN; ++j) acc[i][j] = (floatx4){0.f, 0.f, 0.f, 0.f};

    const int iters = K / BK;
    loadTiles(0);
    writeTiles();
    __syncthreads();

    for (int it = 0; it < iters; ++it) {
        if (it + 1 < iters) loadTiles((it + 1) * BK);

        short8 ah[FM], bh[FN], al[SPLIT ? FM : 1], bl[SPLIT ? FN : 1];
#pragma unroll
        for (int i = 0; i < FM; ++i) {
            ah[i] = *(const short8*)&AsH[(wm + i * 16 + l15) * BK + quad * 8];
            if (SPLIT) al[i] = *(const short8*)&AsL[(wm + i * 16 + l15) * BK + quad * 8];
        }
#pragma unroll
        for (int j = 0; j < FN; ++j) {
            bh[j] = *(const short8*)&BsH[(wn + j * 16 + l15) * BK + quad * 8];
            if (SPLIT) bl[j] = *(const short8*)&BsL[(wn + j * 16 + l15) * BK + quad * 8];
        }
#pragma unroll
        for (int i = 0; i < FM; ++i)
#pragma unroll
            for (int j = 0; j < FN; ++j) {
                acc[i][j] = __builtin_amdgcn_mfma_f32_16x16x32_bf16(ah[i], bh[j], acc[i][j], 0, 0, 0);
                if (SPLIT) {
                    acc[i][j] = __builtin_amdgcn_mfma_f32_16x16x32_bf16(ah[i], bl[j], acc[i][j], 0, 0, 0);
                    acc[i][j] = __builtin_amdgcn_mfma_f32_16x16x32_bf16(al[i], bh[j], acc[i][j], 0, 0, 0);
                }
            }

        if (it + 1 < iters) {
            __syncthreads();
            writeTiles();
            __syncthreads();
        }
    }

#pragma unroll
    for (int i = 0; i < FM; ++i)
#pragma unroll
        for (int j = 0; j < FN; ++j) {
            const int m = m0 + wm + i * 16 + quad * 4;
            const int n = n0 + wn + j * 16 + l15;
#pragma unroll
            for (int r = 0; r < 4; ++r) {
                const float v = acc[i][j][r];
                const long idx = (long)(m + r) * ldc + n;
                if (OUTMODE == 0) {
                    Cf[idx] = v;
                } else if (OUTMODE == 1 || OUTMODE == 3) {
                    Ch[idx] = f2bf(v);
                } else {
                    const unsigned short hi = f2bf(v);
                    Ch[idx] = hi;
                    Cl[idx] = f2bf(v - bf2f(hi));
                }
            }
        }

    if (OUTMODE == 3) {
        const int slot = (blockIdx.z * gridDim.x + blockIdx.x) * 2 + (wn >> 6);
#pragma unroll
        for (int i = 0; i < FM; ++i)
#pragma unroll
            for (int r = 0; r < 4; ++r) {
                float s = 0.f, q = 0.f;
#pragma unroll
                for (int j = 0; j < FN; ++j) {
                    const float v = acc[i][j][r];
                    s += v; q += v * v;
                }
#pragma unroll
                for (int msk = 1; msk < 16; msk <<= 1) {
                    s += __shfl_xor(s, msk, 64);
                    q += __shfl_xor(q, msk, 64);
                }
                if (l15 == 0) {
                    const int row = m0 + wm + i * 16 + quad * 4 + r;
                    S1[(long)row * 256 + slot] = s;
                    S2[(long)row * 256 + slot] = q;
                }
            }
    }
}

// ---------------- fused scores+softmax+y v2 ----------------
// 256 blocks (b = id&7, qt = id>>3), 4 waves; each wave owns 16 q-rows.
// theta A-frags (hi/lo, K=256) hoisted into registers, loaded once.
// Per key-tile mt (128 keys):
//   S: phi staged in 4 kc-chunks of 64 k (register-prefetched),
//      48 split-MFMAs/wave/chunk -> sacc[8] (16q x 128key).
//   softmax: per-wave in registers (4 shfl chains of 4).
//   PV: G staged in 2 mc-chunks of 64 keys (register-prefetched),
//      P via wave-private LDS (C->A layout), 64 MFMAs/wave.
#define FSTR 72     // phi LDS row stride (64 k + 8 pad)
#define GSTR 72     // G   LDS row stride
#define PSTRP 136   // P   LDS row stride (128 keys + 8 pad)

__global__ __launch_bounds__(256) void fused_attn(
    const unsigned short* __restrict__ thphH,
    const unsigned short* __restrict__ thphL,
    const unsigned short* __restrict__ gbf,
    unsigned short* __restrict__ ybf)
{
    const int N = 2048, P = 256, P2 = 512;
    const int id = blockIdx.x;
    const int b  = id & 7;            // XCD-locality heuristic
    const int qt = id >> 3;
    const int q0 = qt * 64;

    const unsigned short* thB = thphH + (long)b * N * P2;
    const unsigned short* tlB = thphL + (long)b * N * P2;
    const unsigned short* gB  = gbf   + (long)b * P * N;
    unsigned short*       yB  = ybf   + (long)b * N * P;

    __shared__ unsigned short Fh[128 * FSTR], Fl[128 * FSTR];  // phi chunk
    __shared__ unsigned short Gs[256 * GSTR];                  // G chunk
    __shared__ unsigned short Pw[4][16 * PSTRP];               // wave-private P

    const int tid = threadIdx.x;
    const int wid = tid >> 6, lane = tid & 63;
    const int l15 = lane & 15, quad = lane >> 4;

    // theta fragments in registers: wave rows [q0+wid*16, +16), A m = l15
    short8 tHr[8], tLr[8];
    {
        const unsigned short* t1 = thB + (long)(q0 + wid * 16 + l15) * P2;
        const unsigned short* t2 = tlB + (long)(q0 + wid * 16 + l15) * P2;
#pragma unroll
        for (int kt = 0; kt < 8; ++kt) {
            tHr[kt] = *(const short8*)&t1[kt * 32 + quad * 8];
            tLr[kt] = *(const short8*)&t2[kt * 32 + quad * 8];
        }
    }

    float mrun[4], lrun[4];
#pragma unroll
    for (int r = 0; r < 4; ++r) { mrun[r] = -1e30f; lrun[r] = 0.f; }

    floatx4 oacc[16];
#pragma unroll
    for (int p = 0; p < 16; ++p) oacc[p] = (floatx4){0.f, 0.f, 0.f, 0.f};

    // staging: gid = s*256+tid -> row = s*32 + (tid>>3), c8 = (tid&7)*8
    const int prow = tid >> 3, pc8 = (tid & 7) * 8;
    short8 pfH[4], pfL[4], pg[8];

    auto loadPhi = [&](int m0, int kc) {
#pragma unroll
        for (int s = 0; s < 4; ++s) {
            const long o = (long)(m0 + prow + s * 32) * P2 + P + kc * 64 + pc8;
            pfH[s] = *(const short8*)&thB[o];
            pfL[s] = *(const short8*)&tlB[o];
        }
    };
    auto writePhi = [&]() {
#pragma unroll
        for (int s = 0; s < 4; ++s) {
            *(short8*)&Fh[(prow + s * 32) * FSTR + pc8] = pfH[s];
            *(short8*)&Fl[(prow + s * 32) * FSTR + pc8] = pfL[s];
        }
    };
    auto loadG = [&](int m0, int mc) {
#pragma unroll
        for (int s = 0; s < 8; ++s)
            pg[s] = *(const short8*)&gB[(long)(prow + s * 32) * N + m0 + mc * 64 + pc8];
    };
    auto writeG = [&]() {
#pragma unroll
        for (int s = 0; s < 8; ++s)
            *(short8*)&Gs[(prow + s * 32) * GSTR + pc8] = pg[s];
    };

    for (int mt = 0; mt < 16; ++mt) {
        const int m0 = mt * 128;

        // ---- S phase ----
        floatx4 sacc[8];
#pragma unroll
        for (int j = 0; j < 8; ++j) sacc[j] = (floatx4){0.f, 0.f, 0.f, 0.f};

        loadPhi(m0, 0);
        writePhi();
        __syncthreads();
#pragma unroll
        for (int kc = 0; kc < 4; ++kc) {
            if (kc < 3) loadPhi(m0, kc + 1);       // prefetch flies over MFMAs
#pragma unroll
            for (int ks = 0; ks < 2; ++ks) {
                const short8 aH = tHr[kc * 2 + ks];
                const short8 aL = tLr[kc * 2 + ks];
#pragma unroll
                for (int j = 0; j < 8; ++j) {
                    const int ro = (j * 16 + l15) * FSTR + ks * 32 + quad * 8;
                    const short8 bh = *(const short8*)&Fh[ro];
                    const short8 bl = *(const short8*)&Fl[ro];
                    sacc[j] = __builtin_amdgcn_mfma_f32_16x16x32_bf16(aH, bh, sacc[j], 0, 0, 0);
                    sacc[j] = __builtin_amdgcn_mfma_f32_16x16x32_bf16(aH, bl, sacc[j], 0, 0, 0);
                    sacc[j] = __builtin_amdgcn_mfma_f32_16x16x32_bf16(aL, bh, sacc[j], 0, 0, 0);
                }
            }
            if (kc < 3) {
                __syncthreads();
                writePhi();                         // vmcnt wait lands here
                __syncthreads();
            }
        }

        // ---- online softmax (registers only; rows = quad*4+r) ----
        float alpha[4];
#pragma unroll
        for (int r = 0; r < 4; ++r) {
            float v = sacc[0][r];
#pragma unroll
            for (int j = 1; j < 8; ++j) v = fmaxf(v, sacc[j][r]);
            v = fmaxf(v, __shfl_xor(v, 1, 64));
            v = fmaxf(v, __shfl_xor(v, 2, 64));
            v = fmaxf(v, __shfl_xor(v, 4, 64));
            v = fmaxf(v, __shfl_xor(v, 8, 64));
            const float mo = mrun[r];
            const float mn = fmaxf(mo, v);
            mrun[r] = mn;
            alpha[r] = __expf(mo - mn);
        }
        float lpart[4] = {0.f, 0.f, 0.f, 0.f};
#pragma unroll
        for (int j = 0; j < 8; ++j)
#pragma unroll
            for (int r = 0; r < 4; ++r) {
                const float p = __expf(sacc[j][r] - mrun[r]);
                Pw[wid][(quad * 4 + r) * PSTRP + j * 16 + l15] = f2bf(p);
                lpart[r] += p;
            }
#pragma unroll
        for (int r = 0; r < 4; ++r) {
            float s = lpart[r];
            s += __shfl_xor(s, 1, 64);
            s += __shfl_xor(s, 2, 64);
            s += __shfl_xor(s, 4, 64);
            s += __shfl_xor(s, 8, 64);
            lrun[r] = lrun[r] * alpha[r] + s;
        }
#pragma unroll
        for (int p = 0; p < 16; ++p)
#pragma unroll
            for (int r = 0; r < 4; ++r) oacc[p][r] *= alpha[r];

        // ---- PV phase ----
        loadG(m0, 0);
        writeG();
        __syncthreads();
#pragma unroll
        for (int mc = 0; mc < 2; ++mc) {
            if (mc == 0) loadG(m0, 1);             // prefetch
#pragma unroll
            for (int kk = 0; kk < 2; ++kk) {
                const short8 af = *(const short8*)&Pw[wid][l15 * PSTRP + mc * 64 + kk * 32 + quad * 8];
#pragma unroll
                for (int pj = 0; pj < 16; ++pj) {
                    const short8 bg = *(const short8*)&Gs[(pj * 16 + l15) * GSTR + kk * 32 + quad * 8];
                    oacc[pj] = __builtin_amdgcn_mfma_f32_16x16x32_bf16(af, bg, oacc[pj], 0, 0, 0);
                }
            }
            if (mc == 0) {
                __syncthreads();
                writeG();
                __syncthreads();
            }
        }
    }

    // ---- finalize: O / l -> yT bf16 ----
    float linv[4];
#pragma unroll
    for (int r = 0; r < 4; ++r) linv[r] = 1.0f / lrun[r];
#pragma unroll
    for (int pj = 0; pj < 16; ++pj)
#pragma unroll
        for (int r = 0; r < 4; ++r) {
            const int row = q0 + wid * 16 + quad * 4 + r;
            const int col = pj * 16 + l15;
            yB[(long)row * P + col] = f2bf(oacc[pj][r] * linv[r]);
        }
}

// ---------------- BN finalize + apply ----------------
__global__ __launch_bounds__(256) void bn_finalize(
    const float* __restrict__ p1, const float* __restrict__ p2,
    float* __restrict__ mean, float* __restrict__ rstd, float cnt)
{
    const int c = blockIdx.x, t = threadIdx.x;
    __shared__ float rs[256], rq[256];
    rs[t] = p1[(long)c * 256 + t];
    rq[t] = p2[(long)c * 256 + t];
    __syncthreads();
    for (int st = 128; st > 0; st >>= 1) {
        if (t < st) { rs[t] += rs[t + st]; rq[t] += rq[t + st]; }
        __syncthreads();
    }
    if (t == 0) {
        const float m = rs[0] / cnt;
        mean[c] = m;
        rstd[c] = rsqrtf(rq[0] / cnt - m * m + 1e-5f);
    }
}

__global__ __launch_bounds__(256) void bn_apply_bf(
    const unsigned short* __restrict__ z, const float* __restrict__ x,
    const float* __restrict__ mean, const float* __restrict__ rstd,
    const float* __restrict__ gamma, const float* __restrict__ beta,
    float* __restrict__ out, int C, int N)
{
    const long i = ((long)blockIdx.x * 256 + threadIdx.x) * 8;
    const int c = (int)((i / N) % C);
    const float mu = mean[c], rs = rstd[c], ga = gamma[c], be = beta[c];
    const ushort4 z0 = *(const ushort4*)&z[i];
    const ushort4 z1 = *(const ushort4*)&z[i + 4];
    const float4 x0 = *(const float4*)&x[i];
    const float4 x1 = *(const float4*)&x[i + 4];
    float4 o0, o1;
    o0.x = (bf2f(z0.x) - mu) * rs * ga + be + x0.x;
    o0.y = (bf2f(z0.y) - mu) * rs * ga + be + x0.y;
    o0.z = (bf2f(z0.z) - mu) * rs * ga + be + x0.z;
    o0.w = (bf2f(z0.w) - mu) * rs * ga + be + x0.w;
    o1.x = (bf2f(z1.x) - mu) * rs * ga + be + x1.x;
    o1.y = (bf2f(z1.y) - mu) * rs * ga + be + x1.y;
    o1.z = (bf2f(z1.z) - mu) * rs * ga + be + x1.z;
    o1.w = (bf2f(z1.w) - mu) * rs * ga + be + x1.w;
    *(float4*)&out[i] = o0;
    *(float4*)&out[i + 4] = o1;
}

extern "C" void kernel_launch(void* const* d_in, const int* in_sizes, int n_in,
                              void* d_out, int out_size, void* d_ws, size_t ws_size,
                              hipStream_t stream)
{
    const int B = 8, C = 512, N = 2048, P = 256;
    const float* x      = (const float*)d_in[0];
    const float* Wg     = (const float*)d_in[1];
    const float* Wtheta = (const float*)d_in[2];
    const float* Wphi   = (const float*)d_in[3];
    const float* Wz     = (const float*)d_in[4];
    const float* gamma  = (const float*)d_in[5];
    const float* beta   = (const float*)d_in[6];
    float* out = (float*)d_out;

    // ---- workspace layout (float units), same as round 9 ----
    float* ws = (float*)d_ws;
    const long NCle = (long)N * C;            // 1,048,576 per batch (= N*2P)
    const long NP   = (long)N * P;            // 524,288 per batch
    const long R0   = (long)B * NCle;         // 8.39M floats
    unsigned short* xtH   = (unsigned short*)ws;                // B*N*C
    unsigned short* xtL   = xtH + B * NCle;
    unsigned short* zbf   = (unsigned short*)ws;                // aliases xt (dead)
    unsigned short* thphH = (unsigned short*)(ws + R0);         // B*N*2P
    unsigned short* thphL = thphH + B * NCle;                   // B*N*2P
    unsigned short* gbf   = (unsigned short*)(ws + 2 * R0);     // B*P*N
    unsigned short* fbf   = gbf + B * NP;                       // (unused)
    unsigned short* ybf   = fbf + (long)B * N * N;              // B*N*P
    unsigned short* W2H   = ybf + B * NP;                       // 2P*C
    unsigned short* W2L   = W2H + 2L * P * C;
    unsigned short* WgB   = W2L + 2L * P * C;                   // P*C
    unsigned short* WzB   = WgB + (long)P * C;
    // BN scratch aliases thph region (dead after fused_attn): [C][256] x2
    float*          bnp1  = ws + R0;
    float*          bnp2  = bnp1 + (long)C * 256;
    float*          mean  = bnp2 + (long)C * 256;
    float*          rstd  = mean + C;

    const long sX = (long)C * N;
    const int  P2 = 2 * P;

    // 1: transpose+split x -> xT hi/lo [B][N][C]
    transpose_split<<<dim3(N / 32, C / 32, B), 256, 0, stream>>>(x, xtH, xtL, C, N);
    // 2: weight preps
    split_w2<<<(2 * P * C + 255) / 256, 256, 0, stream>>>(Wtheta, Wphi, W2H, W2L, P * C);
    cast_bf16<<<P * C / 1024, 256, 0, stream>>>(Wg, WgB);
    cast_bf16<<<P * C / 1024, 256, 0, stream>>>(Wz, WzB);

    // 3: thph [B][N][2P] = xT @ W2^T (split in/out); 128x128, 512 blocks
    mfma_gemm<true, 2, 4, 4><<<dim3(P2 / 128, N / 128, B), 256, 0, stream>>>(
        xtH, xtL, W2H, W2L, thphH, thphL, C, C, C, P2, NCle, 0, NCle, nullptr, nullptr);
    // 4: g [B][P][N] = Wg @ xT^T (plain, bf16 out); 64x128, 512 blocks
    mfma_gemm<false, 1, 2, 4><<<dim3(N / 128, P / 64, B), 256, 0, stream>>>(
        WgB, WgB, xtH, xtH, gbf, gbf, C, C, C, N, 0, NCle, NP, nullptr, nullptr);

    // 5: fused scores+softmax+y -> yT [B][N][P] bf16 (256 blocks, 1/CU)
    fused_attn<<<dim3(256), 256, 0, stream>>>(thphH, thphL, gbf, ybf);

    // 6: z [B][C][N] bf16 = Wz @ yT^T, BN partials (thph dead now)
    mfma_gemm<false, 3, 4, 4><<<dim3(N / 128, C / 128, B), 256, 0, stream>>>(
        WzB, WzB, ybf, ybf, zbf, zbf, P, P, P, N, 0, NP, sX, bnp1, bnp2);

    // 7: BN finalize + apply + residual
    bn_finalize<<<C, 256, 0, stream>>>(bnp1, bnp2, mean, rstd, (float)B * N);
    bn_apply_bf<<<(int)((B * sX) / 2048), 256, 0, stream>>>(zbf, x, mean, rstd, gamma, beta, out, C, N);
}